// Round 8
// baseline (789.490 us; speedup 1.0000x reference)
//
#include <hip/hip_runtime.h>
#include <hip/hip_cooperative_groups.h>

namespace cg = cooperative_groups;

#define N_NODES 100000
#define N_EDGES 3200000
#define N_FEAT 512
#define HIDDEN 16
#define N_CLASSES 40

// ---- 2-level counting sort, fused into ONE cooperative kernel ----
// 391 chunks of 256 nodes; 256 staging slices of 12500 edges.
// grid = 256 WGs x 512 thr (1 WG/CU -> co-residency guaranteed).
#define CH3   256
#define NCHK  391                  // ceil(100000/256)
#define NS2   256
#define SLICE2 (N_EDGES / NS2)     // 12500
#define SL4_2  (SLICE2 / 4)        // 3125
#define RS_WGS 196                 // ceil(100000/512) row_start scan blocks

typedef int v4i __attribute__((ext_vector_type(4)));
typedef int v2i __attribute__((ext_vector_type(2)));

__global__ __launch_bounds__(512) void k_build(
    const int* __restrict__ src, const int* __restrict__ dst,
    int* __restrict__ cnt_sc, int* __restrict__ sbase, int* __restrict__ tot,
    int* __restrict__ cb, int* __restrict__ deg, float* __restrict__ dinv,
    int* __restrict__ bsum, int* __restrict__ boff, int* __restrict__ row_start,
    int2* __restrict__ staged, int2* __restrict__ edge_data)
{
    cg::grid_group grid = cg::this_grid();
    __shared__ int   sA[NCHK];   // hist / curpos / cnt / cursors / scan temps
    __shared__ float sB[CH3];    // dinv cache in P7
    const int tid  = threadIdx.x;
    const int wg   = blockIdx.x;
    const int lane = tid & 63, wv = tid >> 6;

    // ---- P1: per-(slice wg, chunk) histogram -> cnt_sc ----
    for (int i = tid; i < NCHK; i += 512) sA[i] = 0;
    __syncthreads();
    {
        const v4i* dp = reinterpret_cast<const v4i*>(dst + wg * SLICE2);
        for (int i = tid; i < SL4_2; i += 512) {
            v4i d4 = __builtin_nontemporal_load(dp + i);
            atomicAdd(&sA[(unsigned)d4.x >> 8], 1);
            atomicAdd(&sA[(unsigned)d4.y >> 8], 1);
            atomicAdd(&sA[(unsigned)d4.z >> 8], 1);
            atomicAdd(&sA[(unsigned)d4.w >> 8], 1);
        }
        __syncthreads();
        for (int i = tid; i < NCHK; i += 512) cnt_sc[wg * NCHK + i] = sA[i];
    }
    grid.sync();

    // ---- P2: per-chunk exclusive scan over slices (one wave per chunk) ----
    {
        int c = wg * 8 + wv;
        if (c < NCHK) {
            int carry = 0;
            #pragma unroll
            for (int r = 0; r < 4; r++) {
                int s = r * 64 + lane;
                int v = cnt_sc[s * NCHK + c];
                int sc = v;
                #pragma unroll
                for (int off = 1; off < 64; off <<= 1) {
                    int t = __shfl_up(sc, off, 64);
                    if (lane >= off) sc += t;
                }
                sbase[s * NCHK + c] = carry + sc - v;   // exclusive within chunk
                carry += __shfl(sc, 63, 64);
            }
            if (lane == 0) tot[c] = carry;
        }
    }
    grid.sync();

    // ---- P3: scan tot[391] -> cb[0..391] (WG 0 only) ----
    if (wg == 0) {
        int v = (tid < NCHK) ? tot[tid] : 0;
        int sc = v;
        #pragma unroll
        for (int off = 1; off < 64; off <<= 1) {
            int t = __shfl_up(sc, off, 64);
            if (lane >= off) sc += t;
        }
        if (lane == 63) sA[wv] = sc;
        __syncthreads();
        int pre = 0;
        #pragma unroll
        for (int w = 0; w < 8; w++) pre += (w < wv) ? sA[w] : 0;
        int excl = pre + sc - v;
        if (tid < NCHK) cb[tid] = excl;
        if (tid == NCHK - 1) cb[NCHK] = excl + v;   // = N_EDGES
    }
    grid.sync();

    // ---- P4: stage edges chunk-major (LDS cursors, append streams) ----
    {
        for (int c = tid; c < NCHK; c += 512)
            sA[c] = cb[c] + sbase[wg * NCHK + c];
        __syncthreads();
        const v4i* dp = reinterpret_cast<const v4i*>(dst + wg * SLICE2);
        const v4i* sp = reinterpret_cast<const v4i*>(src + wg * SLICE2);
        for (int i = tid; i < SL4_2; i += 512) {
            v4i d4 = __builtin_nontemporal_load(dp + i);
            v4i s4 = __builtin_nontemporal_load(sp + i);
            int p0 = atomicAdd(&sA[(unsigned)d4.x >> 8], 1);
            staged[p0] = make_int2(s4.x, d4.x);
            int p1 = atomicAdd(&sA[(unsigned)d4.y >> 8], 1);
            staged[p1] = make_int2(s4.y, d4.y);
            int p2 = atomicAdd(&sA[(unsigned)d4.z >> 8], 1);
            staged[p2] = make_int2(s4.z, d4.z);
            int p3 = atomicAdd(&sA[(unsigned)d4.w >> 8], 1);
            staged[p3] = make_int2(s4.w, d4.w);
        }
    }
    grid.sync();

    // ---- P5: degree + dinv per chunk from the (L2-hot) staged buffer ----
    for (int c = wg; c < NCHK; c += NS2) {
        int base = c << 8;
        int lim = N_NODES - base; if (lim > CH3) lim = CH3;
        if (tid < CH3) sA[tid] = 0;
        __syncthreads();
        int beg = cb[c], end = cb[c + 1];
        const v2i* stp = reinterpret_cast<const v2i*>(staged);
        for (int i = beg + tid; i < end; i += 512) {
            v2i e = stp[i];
            atomicAdd(&sA[e.y - base], 1);
        }
        __syncthreads();
        if (tid < lim) {
            int d = sA[tid];
            deg[base + tid] = d;
            dinv[base + tid] = rsqrtf((float)(d + 1));  // +1 self-loop
        }
        __syncthreads();
    }
    grid.sync();

    // ---- P6a: per-WG sums of deg (512 nodes/WG) ----
    if (wg < RS_WGS) {
        int i = wg * 512 + tid;
        int v = (i < N_NODES) ? deg[i] : 0;
        int sc = v;
        #pragma unroll
        for (int off = 1; off < 64; off <<= 1) {
            int t = __shfl_up(sc, off, 64);
            if (lane >= off) sc += t;
        }
        if (lane == 63) sA[wv] = sc;
        __syncthreads();
        if (tid == 0) {
            int t8 = 0;
            #pragma unroll
            for (int w = 0; w < 8; w++) t8 += sA[w];
            bsum[wg] = t8;
        }
    }
    grid.sync();

    // ---- P6b: scan bsum[196] -> boff (WG 0) ----
    if (wg == 0) {
        int v = (tid < RS_WGS) ? bsum[tid] : 0;
        int sc = v;
        #pragma unroll
        for (int off = 1; off < 64; off <<= 1) {
            int t = __shfl_up(sc, off, 64);
            if (lane >= off) sc += t;
        }
        if (lane == 63) sA[wv] = sc;
        __syncthreads();
        int pre = 0;
        #pragma unroll
        for (int w = 0; w < 8; w++) pre += (w < wv) ? sA[w] : 0;
        if (tid < RS_WGS) boff[tid] = pre + sc - v;  // exclusive
    }
    grid.sync();

    // ---- P6c: row_start = boff[wg] + in-WG exclusive scan ----
    if (wg < RS_WGS) {
        int i = wg * 512 + tid;
        int v = (i < N_NODES) ? deg[i] : 0;
        int sc = v;
        #pragma unroll
        for (int off = 1; off < 64; off <<= 1) {
            int t = __shfl_up(sc, off, 64);
            if (lane >= off) sc += t;
        }
        if (lane == 63) sA[wv] = sc;
        __syncthreads();
        int pre = 0;
        #pragma unroll
        for (int w = 0; w < 8; w++) pre += (w < wv) ? sA[w] : 0;
        int excl = pre + sc - v;
        if (i < N_NODES) row_start[i] = boff[wg] + excl;
        if (i == N_NODES) row_start[N_NODES] = N_EDGES;
        __syncthreads();
    }
    grid.sync();

    // ---- P7: scatter staged -> edge_data (CSR) via LDS cursors ----
    for (int c = wg; c < NCHK; c += NS2) {
        int base = c << 8;
        int lim = N_NODES - base; if (lim > CH3) lim = CH3;
        if (tid < lim) {
            sA[tid] = row_start[base + tid];
            sB[tid] = dinv[base + tid];
        }
        __syncthreads();
        int beg = cb[c], end = cb[c + 1];
        const v2i* stp = reinterpret_cast<const v2i*>(staged);
        for (int i = beg + tid; i < end; i += 512) {
            v2i e = __builtin_nontemporal_load(stp + i);   // last read of staged
            int nl = e.y - base;
            float nrm = dinv[e.x] * sB[nl];
            int slot = atomicAdd(&sA[nl], 1);
            edge_data[slot] = make_int2(e.x, __float_as_int(nrm));
        }
        __syncthreads();
    }
}

// ---------------- GEMM1: h1[N,16] = x[N,512] @ W1[512,16] ----------------

#define KC 32
#define LDSW 36

__global__ __launch_bounds__(256) void k_gemm1(const float* __restrict__ x,
                                               const float* __restrict__ W1,
                                               float* __restrict__ h1) {
    __shared__ float xs[256 * LDSW];
    int tid = threadIdx.x;
    int row = blockIdx.x * 256 + tid;

    float acc[HIDDEN];
    #pragma unroll
    for (int j = 0; j < HIDDEN; j++) acc[j] = 0.f;

    int s_sub = tid >> 3;  // 0..31 staging row-sub
    int s_k4  = tid & 7;   // 0..7  staging k4

    for (int kc = 0; kc < N_FEAT; kc += KC) {
        __syncthreads();  // previous chunk's reads done before overwrite
        #pragma unroll
        for (int l = 0; l < 8; l++) {
            int srow = s_sub + l * 32;
            int grow = blockIdx.x * 256 + srow;
            int gr = grow < N_NODES ? grow : N_NODES - 1;  // clamp
            float4 v = *reinterpret_cast<const float4*>(
                x + (size_t)gr * N_FEAT + kc + s_k4 * 4);
            *reinterpret_cast<float4*>(&xs[srow * LDSW + s_k4 * 4]) = v;
        }
        __syncthreads();

        const float* Wc = W1 + kc * HIDDEN;  // wave-uniform
        #pragma unroll
        for (int k4 = 0; k4 < 8; k4++) {
            float4 xv = *reinterpret_cast<const float4*>(&xs[tid * LDSW + k4 * 4]);
            const float* w0 = Wc + (k4 * 4 + 0) * HIDDEN;
            const float* w1 = Wc + (k4 * 4 + 1) * HIDDEN;
            const float* w2 = Wc + (k4 * 4 + 2) * HIDDEN;
            const float* w3 = Wc + (k4 * 4 + 3) * HIDDEN;
            #pragma unroll
            for (int j = 0; j < HIDDEN; j++) {
                acc[j] += xv.x * w0[j];
                acc[j] += xv.y * w1[j];
                acc[j] += xv.z * w2[j];
                acc[j] += xv.w * w3[j];
            }
        }
    }

    if (row < N_NODES) {
        float4* op = reinterpret_cast<float4*>(h1 + (size_t)row * HIDDEN);
        #pragma unroll
        for (int q = 0; q < 4; q++)
            op[q] = make_float4(acc[q*4+0], acc[q*4+1], acc[q*4+2], acc[q*4+3]);
    }
}

// ---------------- CSR aggregation: one WAVE per node ----------------

template <bool RELU>
__global__ __launch_bounds__(256) void k_aggw(const int2* __restrict__ edge_data,
                                              const int* __restrict__ row_start,
                                              const float* __restrict__ dinv,
                                              const float* __restrict__ h,
                                              const float* __restrict__ bias,
                                              float* __restrict__ out) {
    int lane = threadIdx.x & 63;
    int node = blockIdx.x * 4 + (threadIdx.x >> 6);
    int sub = lane >> 4, j = lane & 15;
    int beg = row_start[node], end = row_start[node + 1];
    float ds = dinv[node];
    float acc = (sub == 0) ? h[(size_t)node * HIDDEN + j] * (ds * ds) : 0.f;
    int i = beg + sub;
    for (; i + 12 < end; i += 16) {
        int2 ea = edge_data[i];
        int2 eb = edge_data[i + 4];
        int2 ec = edge_data[i + 8];
        int2 ed = edge_data[i + 12];
        float va = h[(size_t)ea.x * HIDDEN + j];
        float vb = h[(size_t)eb.x * HIDDEN + j];
        float vc = h[(size_t)ec.x * HIDDEN + j];
        float vd = h[(size_t)ed.x * HIDDEN + j];
        acc += va * __int_as_float(ea.y);
        acc += vb * __int_as_float(eb.y);
        acc += vc * __int_as_float(ec.y);
        acc += vd * __int_as_float(ed.y);
    }
    for (; i < end; i += 4) {
        int2 e = edge_data[i];
        acc += h[(size_t)e.x * HIDDEN + j] * __int_as_float(e.y);
    }
    acc += __shfl_xor(acc, 16, 64);
    acc += __shfl_xor(acc, 32, 64);
    if (sub == 0) {
        if (RELU) acc = fmaxf(acc + bias[j], 0.f);
        out[(size_t)node * HIDDEN + j] = acc;
    }
}

// ---------------- final: out = agg2 @ W2 + b2, log_softmax ----------------

__global__ __launch_bounds__(256) void k_out(const float* __restrict__ agg2,
                                             const float* __restrict__ W2,
                                             const float* __restrict__ b2,
                                             float* __restrict__ out) {
    int r = blockIdx.x * 256 + threadIdx.x;
    if (r >= N_NODES) return;
    float a[HIDDEN];
    const float4* ap = reinterpret_cast<const float4*>(agg2 + (size_t)r * HIDDEN);
    #pragma unroll
    for (int q = 0; q < 4; q++) {
        float4 v = ap[q];
        a[q * 4 + 0] = v.x; a[q * 4 + 1] = v.y;
        a[q * 4 + 2] = v.z; a[q * 4 + 3] = v.w;
    }
    float acc[N_CLASSES];
    #pragma unroll
    for (int jj = 0; jj < N_CLASSES; jj++) acc[jj] = b2[jj];
    #pragma unroll
    for (int kk = 0; kk < HIDDEN; kk++) {
        float av = a[kk];
        #pragma unroll
        for (int jj = 0; jj < N_CLASSES; jj++)
            acc[jj] += av * W2[kk * N_CLASSES + jj];  // uniform -> scalar loads
    }
    float m = -1e30f;
    #pragma unroll
    for (int jj = 0; jj < N_CLASSES; jj++) m = fmaxf(m, acc[jj]);
    float sum = 0.f;
    #pragma unroll
    for (int jj = 0; jj < N_CLASSES; jj++) sum += __expf(acc[jj] - m);
    float l = m + __logf(sum);
    float4* op = reinterpret_cast<float4*>(out + (size_t)r * N_CLASSES);
    #pragma unroll
    for (int q = 0; q < N_CLASSES / 4; q++) {
        op[q] = make_float4(acc[q*4+0] - l, acc[q*4+1] - l,
                            acc[q*4+2] - l, acc[q*4+3] - l);
    }
}

// ---------------- launch ----------------

extern "C" void kernel_launch(void* const* d_in, const int* in_sizes, int n_in,
                              void* d_out, int out_size, void* d_ws, size_t ws_size,
                              hipStream_t stream) {
    const float* x  = (const float*)d_in[0];
    const int*   ei = (const int*)d_in[1];   // int64 ref -> int32 in harness
    const float* W1 = (const float*)d_in[2];
    const float* b1 = (const float*)d_in[3];
    const float* W2 = (const float*)d_in[4];
    const float* b2 = (const float*)d_in[5];
    const int* src = ei;
    const int* dst = ei + N_EDGES;
    float* out = (float*)d_out;

    // workspace layout (256B-aligned, ~60 MB total)
    char* ws = (char*)d_ws;
    size_t off = 0;
    auto alloc = [&](size_t bytes) {
        size_t o = off; off = (off + bytes + 255) & ~(size_t)255; return o;
    };
    float* dinv      = (float*)(ws + alloc(sizeof(float) * N_NODES));
    int*   cnt       = (int*)  (ws + alloc(sizeof(int) * N_NODES));
    int*   row_start = (int*)  (ws + alloc(sizeof(int) * (N_NODES + 1)));
    int*   cnt_sc    = (int*)  (ws + alloc(sizeof(int) * NS2 * NCHK));
    int*   sbase     = (int*)  (ws + alloc(sizeof(int) * NS2 * NCHK));
    int*   cb        = (int*)  (ws + alloc(sizeof(int) * (NCHK + 1)));
    int*   tot       = (int*)  (ws + alloc(sizeof(int) * NCHK));
    // staged region (25.6 MB) aliases h1+rbuf+pad: staged is fully consumed
    // inside k_build (P7) before gemm1 writes h1. In-order stream.
    int2*  staged    = (int2*) (ws + alloc(sizeof(int2) * N_EDGES));
    float* h1        = (float*)(ws + off - (size_t)N_EDGES * sizeof(int2));
    float* rbuf      = h1 + (size_t)N_NODES * HIDDEN;
    int2*  edge_data = (int2*) (ws + alloc(sizeof(int2) * N_EDGES));
    float* agg2      = (float*)(ws + alloc(sizeof(float) * N_NODES * HIDDEN));
    int*   bsum      = (int*)  (ws + alloc(sizeof(int) * RS_WGS));
    int*   boff      = (int*)  (ws + alloc(sizeof(int) * RS_WGS));

    const int nodeBlocks = (N_NODES + 255) / 256;   // 391
    const int aggBlocks  = N_NODES / 4;             // 25000

    void* args[] = {(void*)&src, (void*)&dst, (void*)&cnt_sc, (void*)&sbase,
                    (void*)&tot, (void*)&cb, (void*)&cnt, (void*)&dinv,
                    (void*)&bsum, (void*)&boff, (void*)&row_start,
                    (void*)&staged, (void*)&edge_data};
    hipLaunchCooperativeKernel(reinterpret_cast<void*>(k_build),
                               dim3(NS2), dim3(512), args, 0, stream);

    k_gemm1<<<nodeBlocks, 256, 0, stream>>>(x, W1, h1);
    k_aggw<true><<<aggBlocks, 256, 0, stream>>>(edge_data, row_start, dinv, h1, b1, rbuf);
    k_aggw<false><<<aggBlocks, 256, 0, stream>>>(edge_data, row_start, dinv, rbuf, nullptr, agg2);
    k_out<<<nodeBlocks, 256, 0, stream>>>(agg2, W2, b2, out);
}